// Round 1
// baseline (399.465 us; speedup 1.0000x reference)
//
#include <hip/hip_runtime.h>

// AngleEnsemble: von Mises mean-shift over softmaxed bin mixture + tiny MLP.
// Layout: 1 wave handles 2 batch rows (32 lanes per row, <=12 bins/lane).
// All trig removed: direction kept as (cos,sin) = (X,Y)*rsqrt(X^2+Y^2);
// w folded into exp2 argument in log2 domain (scales cancel in normalization).

constexpr int NBINS = 360;
constexpr int BATCH = 65536;
constexpr int MMIX  = 3;
constexpr float K2E  = 1.4426950408889634f;   // log2(e)
constexpr float KAP2 = 14.426950408889634f;   // KAPPA * log2(e)

__device__ __forceinline__ float g32_sum(float v) {
#pragma unroll
  for (int m = 16; m >= 1; m >>= 1) v += __shfl_xor(v, m, 64);
  return v;
}
__device__ __forceinline__ float g32_max(float v) {
#pragma unroll
  for (int m = 16; m >= 1; m >>= 1) v = fmaxf(v, __shfl_xor(v, m, 64));
  return v;
}
__device__ __forceinline__ float w64_sum(float v) {
#pragma unroll
  for (int m = 32; m >= 1; m >>= 1) v += __shfl_xor(v, m, 64);
  return v;
}

__global__ __launch_bounds__(256) void angle_kernel(
    const float* __restrict__ logits, const float* __restrict__ sinv,
    const float* __restrict__ W1, const float* __restrict__ B1,
    const float* __restrict__ W2, const float* __restrict__ B2,
    float* __restrict__ out)
{
  const int lane = threadIdx.x & 63;
  const int p    = lane & 31;          // index within 32-lane group
  const int half = lane >> 5;          // which row of the pair
  const int wid  = blockIdx.x * (blockDim.x >> 6) + (threadIdx.x >> 6);
  const int nw   = gridDim.x * (blockDim.x >> 6);

  // Per-lane bin tables: bins 2*(p+32j)+t for j<5, tail bins 320+2p+t (p<20).
  // Tables pre-scaled by KAPPA*log2(e); scale cancels in normalization.
  float ksn[12], kcn[12];
#pragma unroll
  for (int j = 0; j < 6; ++j) {
    const int chunk  = (j < 5) ? (p + 32 * j) : (160 + p);
    const bool valid = (j < 5) || (p < 20);
#pragma unroll
    for (int t = 0; t < 2; ++t) {
      const int n = 2 * chunk + t;
      const float th = (6.2831855f * (float)n) / 360.0f;  // match jnp f32 path
      float s, c;
      sincosf(th, &s, &c);
      ksn[2 * j + t] = valid ? KAP2 * s : 0.0f;
      kcn[2 * j + t] = valid ? KAP2 * c : 0.0f;
    }
  }

  // MLP weights: lane owns hidden cols {lane, lane+64}. Loaded once per wave.
  float w1a[4], w1b[4];
#pragma unroll
  for (int i = 0; i < 4; ++i) {
    w1a[i] = W1[i * 128 + lane];
    w1b[i] = W1[i * 128 + 64 + lane];
  }
  const float b1a = B1[lane], b1b = B1[lane + 64];
  const float w2a0 = W2[lane * 2 + 0], w2a1 = W2[lane * 2 + 1];
  const float w2b0 = W2[(lane + 64) * 2 + 0], w2b1 = W2[(lane + 64) * 2 + 1];
  const float b20 = B2[0], b21 = B2[1];

  const float2* lg2 = reinterpret_cast<const float2*>(logits);
  const float2* sv2 = reinterpret_cast<const float2*>(sinv);
  float2* out2 = reinterpret_cast<float2*>(out);

  for (int pr = wid; pr < BATCH / 2; pr += nw) {
    const int b = 2 * pr + half;

    float w[12];
#pragma unroll
    for (int k = 0; k < 12; ++k) w[k] = 0.0f;

    // --- softmax over N per mixture component, accumulate mixture weight ---
#pragma unroll
    for (int m = 0; m < MMIX; ++m) {
      const float2* row = lg2 + ((size_t)m * BATCH + b) * (NBINS / 2);
      float lv[12];
#pragma unroll
      for (int j = 0; j < 5; ++j) {
        const float2 v = row[p + 32 * j];
        lv[2 * j] = v.x; lv[2 * j + 1] = v.y;
      }
      if (p < 20) {
        const float2 v = row[160 + p];
        lv[10] = v.x; lv[11] = v.y;
      } else {
        lv[10] = -1e30f; lv[11] = -1e30f;
      }
      float mx = lv[0];
#pragma unroll
      for (int k = 1; k < 12; ++k) mx = fmaxf(mx, lv[k]);
      mx = g32_max(mx);
      float e[12], ssum = 0.0f;
#pragma unroll
      for (int k = 0; k < 12; ++k) {
        e[k] = __builtin_amdgcn_exp2f((lv[k] - mx) * K2E);
        ssum += e[k];
      }
      ssum = g32_sum(ssum);
      const float rs = 1.0f / ssum;
#pragma unroll
      for (int k = 0; k < 12; ++k) w[k] = fmaf(e[k], rs, w[k]);
    }

    // --- init direction: (X,Y) ∝ (w·cos_n, w·sin_n); scale cancels ---
    float X = 0.0f, Y = 0.0f;
#pragma unroll
    for (int k = 0; k < 12; ++k) {
      X = fmaf(w[k], kcn[k], X);
      Y = fmaf(w[k], ksn[k], Y);
    }
    X = g32_sum(X); Y = g32_sum(Y);
    float rinv = __builtin_amdgcn_rsqf(fmaf(X, X, Y * Y));
    float c = X * rinv, s = Y * rinv;

    // log2(w) so the kernel weight folds into one exp2 per bin
    float l2w[12];
#pragma unroll
    for (int k = 0; k < 12; ++k)
      l2w[k] = (w[k] > 0.0f) ? __builtin_amdgcn_logf(w[k]) : -1e30f;

    // --- 10 mean-shift iterations, fully in Cartesian form ---
    for (int it = 0; it < 10; ++it) {
      float nX = 0.0f, nY = 0.0f;
#pragma unroll
      for (int k = 0; k < 12; ++k) {
        const float arg = fmaf(c, kcn[k], fmaf(s, ksn[k], l2w[k]));
        const float ee  = __builtin_amdgcn_exp2f(arg);
        nX = fmaf(ee, kcn[k], nX);
        nY = fmaf(ee, ksn[k], nY);
      }
      nX = g32_sum(nX); nY = g32_sum(nY);
      rinv = __builtin_amdgcn_rsqf(fmaf(nX, nX, nY * nY));
      c = nX * rinv; s = nY * rinv;
    }

    // --- fused MLP head, full wave per row of the pair ---
#pragma unroll
    for (int h = 0; h < 2; ++h) {
      const int bb = 2 * pr + h;
      const float cc = __shfl(c, h * 32, 64);
      const float ss = __shfl(s, h * 32, 64);
      const float2 sv = sv2[bb];
      float ha = fmaf(sv.x, w1a[0], fmaf(sv.y, w1a[1],
                 fmaf(cc, w1a[2], fmaf(ss, w1a[3], b1a))));
      float hb = fmaf(sv.x, w1b[0], fmaf(sv.y, w1b[1],
                 fmaf(cc, w1b[2], fmaf(ss, w1b[3], b1b))));
      ha = fmaxf(ha, 0.0f); hb = fmaxf(hb, 0.0f);
      float o0 = fmaf(ha, w2a0, hb * w2b0);
      float o1 = fmaf(ha, w2a1, hb * w2b1);
      o0 = w64_sum(o0); o1 = w64_sum(o1);
      o0 += b20; o1 += b21;
      const float nrm = fmaxf(sqrtf(fmaf(o0, o0, o1 * o1)), 1e-12f);
      const float inv = 1.0f / nrm;
      if (lane == 0) out2[bb] = make_float2(o0 * inv, o1 * inv);
    }
  }
}

extern "C" void kernel_launch(void* const* d_in, const int* in_sizes, int n_in,
                              void* d_out, int out_size, void* d_ws, size_t ws_size,
                              hipStream_t stream) {
  const float* logits = (const float*)d_in[0];
  const float* sinv   = (const float*)d_in[1];
  const float* W1     = (const float*)d_in[2];
  const float* B1     = (const float*)d_in[3];
  const float* W2     = (const float*)d_in[4];
  const float* B2     = (const float*)d_in[5];
  float* out = (float*)d_out;
  hipLaunchKernelGGL(angle_kernel, dim3(2048), dim3(256), 0, stream,
                     logits, sinv, W1, B1, W2, B2, out);
}